// Round 5
// baseline (257.785 us; speedup 1.0000x reference)
//
#include <hip/hip_runtime.h>

// Problem: B=32, F_IN=64, F_OUT=64, D=512, K=64
// out[(b,o),d] = sum_{k,e} T[(b,o),(k,e)] * W[k,e,d],
// T[(b,o),(k,e)] = sum_i coeff[o,i,k] * x[b,i,e]
// GEMM shape: M=2048, N=512, Kdim=32768 (bf16 MFMA, fp32 accum)

#define KK 32768

typedef __attribute__((ext_vector_type(8))) short bf16x8;
typedef __attribute__((ext_vector_type(4))) float f32x4;

__device__ __forceinline__ unsigned short f2bf(float f) {
  unsigned int u = __float_as_uint(f);
  return (unsigned short)((u + 0x7FFFu + ((u >> 16) & 1u)) >> 16);  // RNE
}

__device__ __forceinline__ void gld16(void* lds, const void* g) {
  __builtin_amdgcn_global_load_lds((const __attribute__((address_space(1))) void*)g,
                                   (__attribute__((address_space(3))) void*)lds,
                                   16, 0, 0);
}

// ---- convert W fp32 [64][512(e)][512(d)] -> WbT bf16 [512(d)][64*512 (k,e)]
__global__ __launch_bounds__(256) void convW(const float* __restrict__ W,
                                             unsigned short* __restrict__ WbT) {
  __shared__ float tile[64][65];
  int bx = blockIdx.x;                 // 64 k * 8 et * 8 dt = 4096
  int k = bx >> 6, et = (bx >> 3) & 7, dt = bx & 7;
  int t = threadIdx.x;
  const float* src = W + ((size_t)k * 512 + (size_t)et * 64) * 512 + dt * 64;
  int rr = t >> 6, cc = t & 63;
#pragma unroll
  for (int p = 0; p < 16; p++) {
    int e = p * 4 + rr;
    tile[e][cc] = src[(size_t)e * 512 + cc];
  }
  __syncthreads();
  int dl = t >> 4, eg = t & 15;
#pragma unroll
  for (int p = 0; p < 4; p++) {
    int d = p * 16 + dl;
    ushort4 v;
    v.x = f2bf(tile[eg * 4 + 0][d]);
    v.y = f2bf(tile[eg * 4 + 1][d]);
    v.z = f2bf(tile[eg * 4 + 2][d]);
    v.w = f2bf(tile[eg * 4 + 3][d]);
    *(ushort4*)(WbT + (size_t)(dt * 64 + d) * KK + k * 512 + et * 64 + eg * 4) = v;
  }
}

// ---- convert x fp32 [32][64(i)][512(e)] -> xT bf16 [32][512(e)][64(i)] (LDS transpose)
__global__ __launch_bounds__(256) void convX(const float* __restrict__ x,
                                             unsigned short* __restrict__ xT) {
  __shared__ unsigned short lds[64 * 130];
  int bx = blockIdx.x;                  // 32 b * 4 ec = 128
  int b = bx >> 2, ec = bx & 3;
  int t = threadIdx.x;
  const float* src = x + (size_t)b * 32768 + ec * 128;
#pragma unroll
  for (int j = 0; j < 32; j++) {
    int idx = j * 256 + t;              // 64 i x 128 e
    int i = idx >> 7, e = idx & 127;
    lds[i * 130 + e] = f2bf(src[(size_t)i * 512 + e]);
  }
  __syncthreads();
  unsigned short* dst = xT + (size_t)b * 32768 + ec * 128 * 64;
#pragma unroll
  for (int j = 0; j < 32; j++) {
    int idx = j * 256 + t;              // 128 e x 64 i
    int e = idx >> 6, i = idx & 63;
    dst[idx] = lds[i * 130 + e];
  }
}

// ---- convert coeff fp32 [64(o)][64(i)][64(k)] -> cb bf16 [64(k)][64(o*64+i)] (LDS transpose)
__global__ __launch_bounds__(256) void convC(const float* __restrict__ c,
                                             unsigned short* __restrict__ cb) {
  __shared__ unsigned short lds[64 * 66];
  int rb = blockIdx.x;                  // 64 blocks over r = o*64+i
  int t = threadIdx.x;
  const float* src = c + (size_t)rb * 4096;
#pragma unroll
  for (int j = 0; j < 16; j++) {
    int idx = j * 256 + t;
    int r = idx >> 6, k = idx & 63;
    lds[r * 66 + k] = f2bf(src[idx]);
  }
  __syncthreads();
#pragma unroll
  for (int j = 0; j < 16; j++) {
    int idx = j * 256 + t;
    int k = idx >> 6, r = idx & 63;
    cb[(size_t)k * 4096 + rb * 64 + r] = lds[r * 66 + k];
  }
}

// ---- T kernel v4: Tb[(b*64+o)][(k*512+e)] = sum_i cb[k][o][i] * xT[b][e][i]
// Operand-swapped MFMA (A = x-frag with m=e, B = c-frag with n=o) so the C/D
// row dim (q*4+r) runs along e (contiguous in Tb) -> direct ushort4 reg->global
// stores, no LDS round-trip. All 4 ck words staged upfront: ONE barrier/block.
__global__ __launch_bounds__(256, 3) void tkern(const unsigned short* __restrict__ xT,
                                                const unsigned short* __restrict__ cb,
                                                unsigned short* __restrict__ Tb) {
  __shared__ unsigned short xe[128 * 64];    // 16 KB, XOR-swizzled chunks
  __shared__ unsigned short ck[4 * 64 * 64]; // 32 KB, XOR-swizzled
  int bx = blockIdx.x;                       // 32 b * 16 kq * 4 eq = 2048
  int eq = bx & 3, kq = (bx >> 2) & 15, b = bx >> 6;
  int t = threadIdx.x;
  {
    const unsigned short* gx = xT + (size_t)b * 32768 + (size_t)eq * 8192;
#pragma unroll
    for (int j = 0; j < 4; j++) {
      int idx = j * 256 + t;
      int e = idx >> 3, cg = (idx & 7) ^ (e & 7);
      gld16((char*)xe + idx * 16, gx + e * 64 + cg * 8);
    }
    const unsigned short* gc = cb + (size_t)(kq * 4) * 4096;  // 4 k-words contiguous
#pragma unroll
    for (int j = 0; j < 8; j++) {
      int idx = j * 256 + t;
      int row = idx >> 3, cg = (idx & 7) ^ (row & 7);         // row = kj*64+o; row&7 == o&7
      gld16((char*)ck + idx * 16, gc + row * 64 + cg * 8);
    }
  }
  __syncthreads();
  int wid = t >> 6, lane = t & 63, q = lane >> 4, l16 = lane & 15;
  // A-frags from xe: A[m=e][k=i], reused across all 4 k-words
  bf16x8 ax[2][2];
#pragma unroll
  for (int ef = 0; ef < 2; ef++)
#pragma unroll
    for (int ks2 = 0; ks2 < 2; ks2++) {
      int e = wid * 32 + ef * 16 + l16;
      int s2 = (ks2 * 4 + q) ^ (e & 7);
      ax[ef][ks2] = *(const bf16x8*)(xe + e * 64 + s2 * 8);
    }
  size_t mbase = (size_t)(b * 64);
#pragma unroll
  for (int kj = 0; kj < 4; kj++) {
    const unsigned short* ckk = ck + kj * 4096;
    bf16x8 bc[4][2];
#pragma unroll
    for (int of = 0; of < 4; of++)
#pragma unroll
      for (int ks2 = 0; ks2 < 2; ks2++) {
        int o = of * 16 + l16;
        int s2 = (ks2 * 4 + q) ^ (o & 7);
        bc[of][ks2] = *(const bf16x8*)(ckk + o * 64 + s2 * 8);
      }
    f32x4 acc[2][4] = {};                    // [ef][of], D[m=e][n=o]
#pragma unroll
    for (int ef = 0; ef < 2; ef++)
#pragma unroll
      for (int of = 0; of < 4; of++)
#pragma unroll
        for (int ks2 = 0; ks2 < 2; ks2++)
          acc[ef][of] = __builtin_amdgcn_mfma_f32_16x16x32_bf16(ax[ef][ks2], bc[of][ks2],
                                                                acc[ef][of], 0, 0, 0);
    // C-layout: row(e) = q*4+r, col(o) = l16 -> 4 consecutive e = one ushort4
    int kcol = (kq * 4 + kj) * 512 + eq * 128 + wid * 32 + q * 4;
#pragma unroll
    for (int ef = 0; ef < 2; ef++)
#pragma unroll
      for (int of = 0; of < 4; of++) {
        ushort4 v;
        v.x = f2bf(acc[ef][of][0]);
        v.y = f2bf(acc[ef][of][1]);
        v.z = f2bf(acc[ef][of][2]);
        v.w = f2bf(acc[ef][of][3]);
        *(ushort4*)(Tb + (mbase + of * 16 + l16) * (size_t)KK + kcol + ef * 16) = v;
      }
  }
}

// ---- big GEMM: out[2048][512] += Tb[M][KK] * WbT[N][KK]^T
// 256x128 tile, BK=64 (128B-pitch swizzle), split-K=16, grid 512 = 2 blocks/CU.
// bx bits: [mt:3][kshi:1][nt:2][kslo:3] -> nt-siblings (A-sharing) at stride 8 = co-XCD.
__global__ __launch_bounds__(256, 2) void gemm_kern(const unsigned short* __restrict__ A,
                                                    const unsigned short* __restrict__ Bt,
                                                    float* __restrict__ out) {
  __shared__ unsigned short As[256 * 64];   // 32 KB, row pitch 128 B
  __shared__ unsigned short Bs[128 * 64];   // 16 KB
  int bx = blockIdx.x;                      // 512
  int kslo = bx & 7, nt = (bx >> 3) & 3, kshi = (bx >> 5) & 1, mt = bx >> 6;
  int ks = kshi * 8 + kslo;
  int m0 = mt * 256, n0 = nt * 128, k0 = ks * 2048;
  int t = threadIdx.x;
  int wid = t >> 6, lane = t & 63, q = lane >> 4, l16 = lane & 15;
  int wm = (wid & 1) * 128, wn = (wid >> 1) * 64;
  f32x4 acc[8][4] = {};
  int srow = t >> 3;
  int cg = (t & 7) ^ (srow & 7);
  const char* gabase = (const char*)(A + (size_t)m0 * KK + k0) + (size_t)srow * 65536 + cg * 16;
  const char* gbbase = (const char*)(Bt + (size_t)n0 * KK + k0) + (size_t)srow * 65536 + cg * 16;
  int sw0 = q ^ (l16 & 7);
  int sw1 = (4 | q) ^ (l16 & 7);
#pragma unroll 1
  for (int kc = 0; kc < 2048; kc += 64) {
    const char* ga = gabase + (size_t)kc * 2;
    const char* gb = gbbase + (size_t)kc * 2;
#pragma unroll
    for (int j = 0; j < 8; j++)
      gld16((char*)As + (j * 256 + t) * 16, ga + (size_t)j * 32 * 65536);
#pragma unroll
    for (int j = 0; j < 4; j++)
      gld16((char*)Bs + (j * 256 + t) * 16, gb + (size_t)j * 32 * 65536);
    __syncthreads();
#pragma unroll
    for (int ks2 = 0; ks2 < 2; ks2++) {
      int slot = ks2 ? sw1 : sw0;
      bf16x8 af[8], bfr[4];
#pragma unroll
      for (int mf = 0; mf < 8; mf++)
        af[mf] = *(const bf16x8*)(As + (wm + mf * 16 + l16) * 64 + slot * 8);
#pragma unroll
      for (int nf = 0; nf < 4; nf++)
        bfr[nf] = *(const bf16x8*)(Bs + (wn + nf * 16 + l16) * 64 + slot * 8);
#pragma unroll
      for (int mf = 0; mf < 8; mf++)
#pragma unroll
        for (int nf = 0; nf < 4; nf++)
          acc[mf][nf] = __builtin_amdgcn_mfma_f32_16x16x32_bf16(af[mf], bfr[nf], acc[mf][nf], 0, 0, 0);
    }
    __syncthreads();
  }
#pragma unroll
  for (int mf = 0; mf < 8; mf++)
#pragma unroll
    for (int nf = 0; nf < 4; nf++)
#pragma unroll
      for (int r = 0; r < 4; r++)
        atomicAdd(&out[(size_t)(m0 + wm + mf * 16 + q * 4 + r) * 512 + n0 + wn + nf * 16 + l16],
                  acc[mf][nf][r]);
}

// ---- fp32 fallback (only if ws too small)
__global__ __launch_bounds__(256) void fallback_kern(const float* __restrict__ x,
                                                     const float* __restrict__ W,
                                                     const float* __restrict__ coeff,
                                                     float* __restrict__ out) {
  __shared__ float ev[64][129];
  int b = blockIdx.x >> 6, k = blockIdx.x & 63;
  int t = threadIdx.x, dl = t & 127, half = t >> 7;
  const float* xb = x + (size_t)b * 64 * 512;
  const float* Wk = W + (size_t)k * 512 * 512;
  for (int dc = 0; dc < 4; dc++) {
    int d = dc * 128 + dl;
    for (int i = half * 32; i < half * 32 + 32; i++) {
      float acc = 0.f;
      const float* xr = xb + (size_t)i * 512;
#pragma unroll 4
      for (int e = 0; e < 512; e++) acc += xr[e] * Wk[(size_t)e * 512 + d];
      ev[i][dl] = acc;
    }
    __syncthreads();
    for (int o = half * 32; o < half * 32 + 32; o++) {
      float s = 0.f;
#pragma unroll 8
      for (int i = 0; i < 64; i++) s += coeff[((size_t)o * 64 + i) * 64 + k] * ev[i][dl];
      atomicAdd(&out[((size_t)(b * 64 + o)) * 512 + d], s);
    }
    __syncthreads();
  }
}

extern "C" void kernel_launch(void* const* d_in, const int* in_sizes, int n_in,
                              void* d_out, int out_size, void* d_ws, size_t ws_size,
                              hipStream_t stream) {
  const float* x = (const float*)d_in[0];
  const float* W = (const float*)d_in[1];
  const float* coeff = (const float*)d_in[2];
  float* out = (float*)d_out;
  const size_t OFF_XT = 33554432;            // WbT: 512*32768*2
  const size_t OFF_CB = OFF_XT + 2097152;    // xT : 32*512*64*2
  const size_t OFF_TB = OFF_CB + 524288;     // cb : 64*64*64*2
  const size_t NEED = OFF_TB + 134217728;    // Tb : 2048*32768*2

  hipMemsetAsync(d_out, 0, (size_t)out_size * sizeof(float), stream);
  if (ws_size >= NEED) {
    unsigned short* WbT = (unsigned short*)d_ws;
    unsigned short* xT  = (unsigned short*)((char*)d_ws + OFF_XT);
    unsigned short* cb  = (unsigned short*)((char*)d_ws + OFF_CB);
    unsigned short* Tb  = (unsigned short*)((char*)d_ws + OFF_TB);
    convX<<<128, 256, 0, stream>>>(x, xT);
    convC<<<64, 256, 0, stream>>>(coeff, cb);
    convW<<<4096, 256, 0, stream>>>(W, WbT);
    tkern<<<2048, 256, 0, stream>>>(xT, cb, Tb);
    gemm_kern<<<512, 256, 0, stream>>>(Tb, WbT, out);
  } else {
    fallback_kern<<<2048, 256, 0, stream>>>(x, W, coeff, out);
  }
}

// Round 6
// 246.867 us; speedup vs baseline: 1.0442x; 1.0442x over previous
//
#include <hip/hip_runtime.h>

// Problem: B=32, F_IN=64, F_OUT=64, D=512, K=64
// out[(b,o),d] = sum_{k,e} T[(b,o),(k,e)] * W[k,e,d],
// T[(b,o),(k,e)] = sum_i coeff[o,i,k] * x[b,i,e]
// GEMM shape: M=2048, N=512, Kdim=32768 (bf16 MFMA, fp32 accum)

#define KK 32768

typedef __attribute__((ext_vector_type(8))) short bf16x8;
typedef __attribute__((ext_vector_type(4))) float f32x4;

__device__ __forceinline__ unsigned short f2bf(float f) {
  unsigned int u = __float_as_uint(f);
  return (unsigned short)((u + 0x7FFFu + ((u >> 16) & 1u)) >> 16);  // RNE
}

__device__ __forceinline__ void gld16(void* lds, const void* g) {
  __builtin_amdgcn_global_load_lds((const __attribute__((address_space(1))) void*)g,
                                   (__attribute__((address_space(3))) void*)lds,
                                   16, 0, 0);
}

// ---- convert W fp32 [64][512(e)][512(d)] -> WbT bf16 [512(d)][64*512 (k,e)]
__global__ __launch_bounds__(256) void convW(const float* __restrict__ W,
                                             unsigned short* __restrict__ WbT) {
  __shared__ float tile[64][65];
  int bx = blockIdx.x;                 // 64 k * 8 et * 8 dt = 4096
  int k = bx >> 6, et = (bx >> 3) & 7, dt = bx & 7;
  int t = threadIdx.x;
  const float* src = W + ((size_t)k * 512 + (size_t)et * 64) * 512 + dt * 64;
  int rr = t >> 6, cc = t & 63;
#pragma unroll
  for (int p = 0; p < 16; p++) {
    int e = p * 4 + rr;
    tile[e][cc] = src[(size_t)e * 512 + cc];
  }
  __syncthreads();
  int dl = t >> 4, eg = t & 15;
#pragma unroll
  for (int p = 0; p < 4; p++) {
    int d = p * 16 + dl;
    ushort4 v;
    v.x = f2bf(tile[eg * 4 + 0][d]);
    v.y = f2bf(tile[eg * 4 + 1][d]);
    v.z = f2bf(tile[eg * 4 + 2][d]);
    v.w = f2bf(tile[eg * 4 + 3][d]);
    *(ushort4*)(WbT + (size_t)(dt * 64 + d) * KK + k * 512 + et * 64 + eg * 4) = v;
  }
}

// ---- convert x fp32 [32][64(i)][512(e)] -> xT bf16 [32][512(e)][64(i)] (LDS transpose)
__global__ __launch_bounds__(256) void convX(const float* __restrict__ x,
                                             unsigned short* __restrict__ xT) {
  __shared__ unsigned short lds[64 * 130];
  int bx = blockIdx.x;                  // 32 b * 4 ec = 128
  int b = bx >> 2, ec = bx & 3;
  int t = threadIdx.x;
  const float* src = x + (size_t)b * 32768 + ec * 128;
#pragma unroll
  for (int j = 0; j < 32; j++) {
    int idx = j * 256 + t;              // 64 i x 128 e
    int i = idx >> 7, e = idx & 127;
    lds[i * 130 + e] = f2bf(src[(size_t)i * 512 + e]);
  }
  __syncthreads();
  unsigned short* dst = xT + (size_t)b * 32768 + ec * 128 * 64;
#pragma unroll
  for (int j = 0; j < 32; j++) {
    int idx = j * 256 + t;              // 128 e x 64 i
    int e = idx >> 6, i = idx & 63;
    dst[idx] = lds[i * 130 + e];
  }
}

// ---- convert coeff fp32 [64(o)][64(i)][64(k)] -> cb bf16 [64(k)][64(o*64+i)] (LDS transpose)
__global__ __launch_bounds__(256) void convC(const float* __restrict__ c,
                                             unsigned short* __restrict__ cb) {
  __shared__ unsigned short lds[64 * 66];
  int rb = blockIdx.x;                  // 64 blocks over r = o*64+i
  int t = threadIdx.x;
  const float* src = c + (size_t)rb * 4096;
#pragma unroll
  for (int j = 0; j < 16; j++) {
    int idx = j * 256 + t;
    int r = idx >> 6, k = idx & 63;
    lds[r * 66 + k] = f2bf(src[idx]);
  }
  __syncthreads();
#pragma unroll
  for (int j = 0; j < 16; j++) {
    int idx = j * 256 + t;
    int k = idx >> 6, r = idx & 63;
    cb[(size_t)k * 4096 + rb * 64 + r] = lds[r * 66 + k];
  }
}

// ---- T kernel v5: Tb[(b*64+o)][(k*512+e)] = sum_i cb[k][o][i] * xT[b][e][i]
// Operand-swapped MFMA (A = x-frag m=e, B = c-frag n=o): C/D rows (q*4+r) run
// along e -> each lane writes its f32x4 as ONE ushort4 ds_write_b64 into ot,
// then ot is copied to global in 256B runs (proven v3 path). All 4 ck words
// staged upfront; xe staged once. LDS 66 KB -> 2 blocks/CU.
__global__ __launch_bounds__(256, 2) void tkern(const unsigned short* __restrict__ xT,
                                                const unsigned short* __restrict__ cb,
                                                unsigned short* __restrict__ Tb) {
  __shared__ unsigned short xe[128 * 64];    // 16 KB, XOR-swizzled chunks
  __shared__ unsigned short ck[4 * 64 * 64]; // 32 KB, XOR-swizzled
  __shared__ unsigned short ot[64 * 132];    // 16.9 KB store staging [o][128 e]
  int bx = blockIdx.x;                       // 32 b * 16 kq * 4 eq = 2048
  int eq = bx & 3, kq = (bx >> 2) & 15, b = bx >> 6;
  int t = threadIdx.x;
  {
    const unsigned short* gx = xT + (size_t)b * 32768 + (size_t)eq * 8192;
#pragma unroll
    for (int j = 0; j < 4; j++) {
      int idx = j * 256 + t;
      int e = idx >> 3, cg = (idx & 7) ^ (e & 7);
      gld16((char*)xe + idx * 16, gx + e * 64 + cg * 8);
    }
    const unsigned short* gc = cb + (size_t)(kq * 4) * 4096;  // 4 k-words contiguous
#pragma unroll
    for (int j = 0; j < 8; j++) {
      int idx = j * 256 + t;
      int row = idx >> 3, cg = (idx & 7) ^ (row & 7);         // row = kj*64+o; row&7 == o&7
      gld16((char*)ck + idx * 16, gc + row * 64 + cg * 8);
    }
  }
  __syncthreads();
  int wid = t >> 6, lane = t & 63, q = lane >> 4, l16 = lane & 15;
  // A-frags from xe: A[m=e][k=i], reused across all 4 k-words
  bf16x8 ax[2][2];
#pragma unroll
  for (int ef = 0; ef < 2; ef++)
#pragma unroll
    for (int ks2 = 0; ks2 < 2; ks2++) {
      int e = wid * 32 + ef * 16 + l16;
      int s2 = (ks2 * 4 + q) ^ (e & 7);
      ax[ef][ks2] = *(const bf16x8*)(xe + e * 64 + s2 * 8);
    }
  size_t mbase = (size_t)(b * 64);
#pragma unroll 1
  for (int kj = 0; kj < 4; kj++) {
    const unsigned short* ckk = ck + kj * 4096;
    bf16x8 bc[4][2];
#pragma unroll
    for (int of = 0; of < 4; of++)
#pragma unroll
      for (int ks2 = 0; ks2 < 2; ks2++) {
        int o = of * 16 + l16;
        int s2 = (ks2 * 4 + q) ^ (o & 7);
        bc[of][ks2] = *(const bf16x8*)(ckk + o * 64 + s2 * 8);
      }
    f32x4 acc[2][4] = {};                    // [ef][of], D[m=e][n=o]
#pragma unroll
    for (int ef = 0; ef < 2; ef++)
#pragma unroll
      for (int of = 0; of < 4; of++)
#pragma unroll
        for (int ks2 = 0; ks2 < 2; ks2++)
          acc[ef][of] = __builtin_amdgcn_mfma_f32_16x16x32_bf16(ax[ef][ks2], bc[of][ks2],
                                                                acc[ef][of], 0, 0, 0);
    __syncthreads();                         // prev kj's ot copies done; ot free
    // C-layout: row(e) = q*4+r, col(o) = l16 -> one ushort4 per (ef,of)
#pragma unroll
    for (int ef = 0; ef < 2; ef++)
#pragma unroll
      for (int of = 0; of < 4; of++) {
        int o = of * 16 + l16;
        int e = wid * 32 + ef * 16 + q * 4;  // local e within 128
        ushort4 v;
        v.x = f2bf(acc[ef][of][0]);
        v.y = f2bf(acc[ef][of][1]);
        v.z = f2bf(acc[ef][of][2]);
        v.w = f2bf(acc[ef][of][3]);
        *(ushort4*)(ot + o * 132 + e) = v;
      }
    __syncthreads();                         // ot ready
    unsigned short* gdst = Tb + mbase * KK + (size_t)(kq * 4 + kj) * 512 + eq * 128;
#pragma unroll
    for (int j = 0; j < 8; j++) {
      int idx = j * 256 + t;                 // 64 o x 32 ushort4-slots -> 256B runs
      int o = idx >> 5, c = idx & 31;
      *(ushort4*)(gdst + (size_t)o * KK + c * 4) = *(const ushort4*)(ot + o * 132 + c * 4);
    }
  }
}

// ---- big GEMM (R4 proven config, verbatim): out[2048][512] += Tb * WbT^T
// 128x128 tile, BK=64, split-K=16 (1024 blocks, 4/CU), single-buffer,
// 128B-pitch XOR swizzle (conflicts 0), ks in low bx bits (co-XCD A-sharing).
__global__ __launch_bounds__(256, 4) void gemm_kern(const unsigned short* __restrict__ A,
                                                    const unsigned short* __restrict__ Bt,
                                                    float* __restrict__ out) {
  __shared__ unsigned short As[128 * 64];   // 16 KB, row pitch 128 B
  __shared__ unsigned short Bs[128 * 64];   // 16 KB
  int bx = blockIdx.x;                      // 16 ks * 4 nt * 16 mt = 1024
  int ks = bx & 15, nt = (bx >> 4) & 3, mt = bx >> 6;
  int m0 = mt * 128, n0 = nt * 128, k0 = ks * 2048;
  int t = threadIdx.x;
  int wid = t >> 6, lane = t & 63, q = lane >> 4, l16 = lane & 15;
  int wm = (wid & 1) * 64, wn = (wid >> 1) * 64;
  f32x4 acc[4][4] = {};
  int srow = t >> 3;
  int cg = (t & 7) ^ (srow & 7);
  const char* gabase = (const char*)(A + (size_t)m0 * KK + k0) + (size_t)srow * 65536 + cg * 16;
  const char* gbbase = (const char*)(Bt + (size_t)n0 * KK + k0) + (size_t)srow * 65536 + cg * 16;
  int sw0 = q ^ (l16 & 7);
  int sw1 = (4 | q) ^ (l16 & 7);
#pragma unroll 1
  for (int kc = 0; kc < 2048; kc += 64) {
    const char* ga = gabase + (size_t)kc * 2;
    const char* gb = gbbase + (size_t)kc * 2;
#pragma unroll
    for (int j = 0; j < 4; j++) {
      gld16((char*)As + (j * 256 + t) * 16, ga + (size_t)j * 32 * 65536);
      gld16((char*)Bs + (j * 256 + t) * 16, gb + (size_t)j * 32 * 65536);
    }
    __syncthreads();
#pragma unroll
    for (int ks2 = 0; ks2 < 2; ks2++) {
      int slot = ks2 ? sw1 : sw0;
      bf16x8 af[4], bfr[4];
#pragma unroll
      for (int fr = 0; fr < 4; fr++)
        af[fr] = *(const bf16x8*)(As + (wm + fr * 16 + l16) * 64 + slot * 8);
#pragma unroll
      for (int fc = 0; fc < 4; fc++)
        bfr[fc] = *(const bf16x8*)(Bs + (wn + fc * 16 + l16) * 64 + slot * 8);
#pragma unroll
      for (int fr = 0; fr < 4; fr++)
#pragma unroll
        for (int fc = 0; fc < 4; fc++)
          acc[fr][fc] = __builtin_amdgcn_mfma_f32_16x16x32_bf16(af[fr], bfr[fc], acc[fr][fc], 0, 0, 0);
    }
    __syncthreads();
  }
#pragma unroll
  for (int fr = 0; fr < 4; fr++)
#pragma unroll
    for (int fc = 0; fc < 4; fc++)
#pragma unroll
      for (int r = 0; r < 4; r++)
        atomicAdd(&out[(size_t)(m0 + wm + fr * 16 + q * 4 + r) * 512 + n0 + wn + fc * 16 + l16],
                  acc[fr][fc][r]);
}

// ---- fp32 fallback (only if ws too small)
__global__ __launch_bounds__(256) void fallback_kern(const float* __restrict__ x,
                                                     const float* __restrict__ W,
                                                     const float* __restrict__ coeff,
                                                     float* __restrict__ out) {
  __shared__ float ev[64][129];
  int b = blockIdx.x >> 6, k = blockIdx.x & 63;
  int t = threadIdx.x, dl = t & 127, half = t >> 7;
  const float* xb = x + (size_t)b * 64 * 512;
  const float* Wk = W + (size_t)k * 512 * 512;
  for (int dc = 0; dc < 4; dc++) {
    int d = dc * 128 + dl;
    for (int i = half * 32; i < half * 32 + 32; i++) {
      float acc = 0.f;
      const float* xr = xb + (size_t)i * 512;
#pragma unroll 4
      for (int e = 0; e < 512; e++) acc += xr[e] * Wk[(size_t)e * 512 + d];
      ev[i][dl] = acc;
    }
    __syncthreads();
    for (int o = half * 32; o < half * 32 + 32; o++) {
      float s = 0.f;
#pragma unroll 8
      for (int i = 0; i < 64; i++) s += coeff[((size_t)o * 64 + i) * 64 + k] * ev[i][dl];
      atomicAdd(&out[((size_t)(b * 64 + o)) * 512 + d], s);
    }
    __syncthreads();
  }
}

extern "C" void kernel_launch(void* const* d_in, const int* in_sizes, int n_in,
                              void* d_out, int out_size, void* d_ws, size_t ws_size,
                              hipStream_t stream) {
  const float* x = (const float*)d_in[0];
  const float* W = (const float*)d_in[1];
  const float* coeff = (const float*)d_in[2];
  float* out = (float*)d_out;
  const size_t OFF_XT = 33554432;            // WbT: 512*32768*2
  const size_t OFF_CB = OFF_XT + 2097152;    // xT : 32*512*64*2
  const size_t OFF_TB = OFF_CB + 524288;     // cb : 64*64*64*2
  const size_t NEED = OFF_TB + 134217728;    // Tb : 2048*32768*2

  hipMemsetAsync(d_out, 0, (size_t)out_size * sizeof(float), stream);
  if (ws_size >= NEED) {
    unsigned short* WbT = (unsigned short*)d_ws;
    unsigned short* xT  = (unsigned short*)((char*)d_ws + OFF_XT);
    unsigned short* cb  = (unsigned short*)((char*)d_ws + OFF_CB);
    unsigned short* Tb  = (unsigned short*)((char*)d_ws + OFF_TB);
    convX<<<128, 256, 0, stream>>>(x, xT);
    convC<<<64, 256, 0, stream>>>(coeff, cb);
    convW<<<4096, 256, 0, stream>>>(W, WbT);
    tkern<<<2048, 256, 0, stream>>>(xT, cb, Tb);
    gemm_kern<<<1024, 256, 0, stream>>>(Tb, WbT, out);
  } else {
    fallback_kern<<<2048, 256, 0, stream>>>(x, W, coeff, out);
  }
}

// Round 7
// 240.263 us; speedup vs baseline: 1.0729x; 1.0275x over previous
//
#include <hip/hip_runtime.h>

// Problem: B=32, F_IN=64, F_OUT=64, D=512, K=64
// out[(b,o),d] = sum_{k,e} T[(b,o),(k,e)] * W[k,e,d],
// T[(b,o),(k,e)] = sum_i coeff[o,i,k] * x[b,i,e]
// GEMM shape: M=2048, N=512, Kdim=32768 (bf16 MFMA, fp32 accum)

#define KK 32768

typedef __attribute__((ext_vector_type(8))) short bf16x8;
typedef __attribute__((ext_vector_type(4))) float f32x4;

__device__ __forceinline__ unsigned short f2bf(float f) {
  unsigned int u = __float_as_uint(f);
  return (unsigned short)((u + 0x7FFFu + ((u >> 16) & 1u)) >> 16);  // RNE
}

__device__ __forceinline__ void gld16(void* lds, const void* g) {
  __builtin_amdgcn_global_load_lds((const __attribute__((address_space(1))) void*)g,
                                   (__attribute__((address_space(3))) void*)lds,
                                   16, 0, 0);
}

// ---- convert W fp32 [64][512(e)][512(d)] -> WbT bf16 [512(d)][64*512 (k,e)]
__global__ __launch_bounds__(256) void convW(const float* __restrict__ W,
                                             unsigned short* __restrict__ WbT) {
  __shared__ float tile[64][65];
  int bx = blockIdx.x;                 // 64 k * 8 et * 8 dt = 4096
  int k = bx >> 6, et = (bx >> 3) & 7, dt = bx & 7;
  int t = threadIdx.x;
  const float* src = W + ((size_t)k * 512 + (size_t)et * 64) * 512 + dt * 64;
  int rr = t >> 6, cc = t & 63;
#pragma unroll
  for (int p = 0; p < 16; p++) {
    int e = p * 4 + rr;
    tile[e][cc] = src[(size_t)e * 512 + cc];
  }
  __syncthreads();
  int dl = t >> 4, eg = t & 15;
#pragma unroll
  for (int p = 0; p < 4; p++) {
    int d = p * 16 + dl;
    ushort4 v;
    v.x = f2bf(tile[eg * 4 + 0][d]);
    v.y = f2bf(tile[eg * 4 + 1][d]);
    v.z = f2bf(tile[eg * 4 + 2][d]);
    v.w = f2bf(tile[eg * 4 + 3][d]);
    *(ushort4*)(WbT + (size_t)(dt * 64 + d) * KK + k * 512 + et * 64 + eg * 4) = v;
  }
}

// ---- fused convX + convC (one launch)
// blocks 0..127:  x fp32 [32][64(i)][512(e)] -> xT bf16 [32][512(e)][64(i)]
// blocks 128..191: coeff fp32 [64(o)][64(i)][64(k)] -> cb bf16 [64(k)][4096(o,i)]
__global__ __launch_bounds__(256) void convXC(const float* __restrict__ x,
                                              const float* __restrict__ c,
                                              unsigned short* __restrict__ xT,
                                              unsigned short* __restrict__ cb) {
  __shared__ unsigned short lds[64 * 130];
  int t = threadIdx.x;
  if (blockIdx.x < 128) {
    int bx = blockIdx.x;                // 32 b * 4 ec
    int b = bx >> 2, ec = bx & 3;
    const float* src = x + (size_t)b * 32768 + ec * 128;
#pragma unroll
    for (int j = 0; j < 32; j++) {
      int idx = j * 256 + t;            // 64 i x 128 e
      int i = idx >> 7, e = idx & 127;
      lds[i * 130 + e] = f2bf(src[(size_t)i * 512 + e]);
    }
    __syncthreads();
    unsigned short* dst = xT + (size_t)b * 32768 + ec * 128 * 64;
#pragma unroll
    for (int j = 0; j < 32; j++) {
      int idx = j * 256 + t;            // 128 e x 64 i
      int e = idx >> 6, i = idx & 63;
      dst[idx] = lds[i * 130 + e];
    }
  } else {
    int rb = blockIdx.x - 128;          // 64 blocks over r = o*64+i
    const float* src = c + (size_t)rb * 4096;
#pragma unroll
    for (int j = 0; j < 16; j++) {
      int idx = j * 256 + t;
      int r = idx >> 6, k = idx & 63;
      lds[r * 66 + k] = f2bf(src[idx]);
    }
    __syncthreads();
#pragma unroll
    for (int j = 0; j < 16; j++) {
      int idx = j * 256 + t;
      int k = idx >> 6, r = idx & 63;
      cb[(size_t)k * 4096 + rb * 64 + r] = lds[r * 66 + k];
    }
  }
}

// ---- T kernel v7: Tb[(b*64+o)][(k*512+e)] = sum_i cb[k][o][i] * xT[b][e][i]
// Operand-swapped MFMA (C/D rows run along e -> ushort4 ds_writes into ot).
// 5 barriers/block (was 9): ck ping-pong staged during compute; ot ping-pong
// with ot[1] aliasing the dead xe region (xe only read into ax frags once).
// LDS 49 KB -> 3 blocks/CU.
__global__ __launch_bounds__(256, 3) void tkern(const unsigned short* __restrict__ xT,
                                                const unsigned short* __restrict__ cb,
                                                unsigned short* __restrict__ Tb) {
  __shared__ unsigned short u0[64 * 132];     // xe [128][64] (16384 B) / ot[1] (16896 B)
  __shared__ unsigned short ck[2][64 * 64];   // 8 KB x2, XOR-swizzled
  __shared__ unsigned short ot0[64 * 132];    // 16896 B
  unsigned short* xe = u0;
  int bx = blockIdx.x;                        // 32 b * 16 kq * 4 eq = 2048
  int eq = bx & 3, kq = (bx >> 2) & 15, b = bx >> 6;
  int t = threadIdx.x;
  {
    const unsigned short* gx = xT + (size_t)b * 32768 + (size_t)eq * 8192;
#pragma unroll
    for (int j = 0; j < 4; j++) {
      int idx = j * 256 + t;
      int e = idx >> 3, cg = (idx & 7) ^ (e & 7);
      gld16((char*)xe + idx * 16, gx + e * 64 + cg * 8);
    }
    const unsigned short* gc = cb + (size_t)(kq * 4) * 4096;
#pragma unroll
    for (int j = 0; j < 2; j++) {
      int idx = j * 256 + t;
      int o = idx >> 3, cg = (idx & 7) ^ (o & 7);
      gld16((char*)ck[0] + idx * 16, gc + o * 64 + cg * 8);
    }
  }
  __syncthreads();                            // barrier 1 of 5
  int wid = t >> 6, lane = t & 63, q = lane >> 4, l16 = lane & 15;
  // A-frags from xe: A[m=e][k=i]; xe dead afterwards (aliased by ot[1] from kj=1 on)
  bf16x8 ax[2][2];
#pragma unroll
  for (int ef = 0; ef < 2; ef++)
#pragma unroll
    for (int ks2 = 0; ks2 < 2; ks2++) {
      int e = wid * 32 + ef * 16 + l16;
      int s2 = (ks2 * 4 + q) ^ (e & 7);
      ax[ef][ks2] = *(const bf16x8*)(xe + e * 64 + s2 * 8);
    }
  size_t mbase = (size_t)(b * 64);
#pragma unroll 1
  for (int kj = 0; kj < 4; kj++) {
    int cur = kj & 1;
    if (kj < 3) {                             // stage next ck during compute
      const unsigned short* gc = cb + (size_t)(kq * 4 + kj + 1) * 4096;
#pragma unroll
      for (int j = 0; j < 2; j++) {
        int idx = j * 256 + t;
        int o = idx >> 3, cg = (idx & 7) ^ (o & 7);
        gld16((char*)ck[cur ^ 1] + idx * 16, gc + o * 64 + cg * 8);
      }
    }
    const unsigned short* ckk = ck[cur];
    bf16x8 bc[4][2];
#pragma unroll
    for (int of = 0; of < 4; of++)
#pragma unroll
      for (int ks2 = 0; ks2 < 2; ks2++) {
        int o = of * 16 + l16;
        int s2 = (ks2 * 4 + q) ^ (o & 7);
        bc[of][ks2] = *(const bf16x8*)(ckk + o * 64 + s2 * 8);
      }
    f32x4 acc[2][4] = {};                     // [ef][of], D[m=e][n=o]
#pragma unroll
    for (int ef = 0; ef < 2; ef++)
#pragma unroll
      for (int of = 0; of < 4; of++)
#pragma unroll
        for (int ks2 = 0; ks2 < 2; ks2++)
          acc[ef][of] = __builtin_amdgcn_mfma_f32_16x16x32_bf16(ax[ef][ks2], bc[of][ks2],
                                                                acc[ef][of], 0, 0, 0);
    unsigned short* ot = cur ? u0 : ot0;      // kj=0 -> ot0 (xe still being read this iter)
    // C-layout: row(e)=q*4+r, col(o)=l16 -> one ushort4 per (ef,of)
#pragma unroll
    for (int ef = 0; ef < 2; ef++)
#pragma unroll
      for (int of = 0; of < 4; of++) {
        int o = of * 16 + l16;
        int e = wid * 32 + ef * 16 + q * 4;
        ushort4 v;
        v.x = f2bf(acc[ef][of][0]);
        v.y = f2bf(acc[ef][of][1]);
        v.z = f2bf(acc[ef][of][2]);
        v.w = f2bf(acc[ef][of][3]);
        *(ushort4*)(ot + o * 132 + e) = v;
      }
    __syncthreads();                          // barriers 2..5
    unsigned short* gdst = Tb + mbase * KK + (size_t)(kq * 4 + kj) * 512 + eq * 128;
#pragma unroll
    for (int j = 0; j < 8; j++) {
      int idx = j * 256 + t;                  // 64 o x 32 ushort4-slots -> 256B runs
      int o = idx >> 5, cc2 = idx & 31;
      *(ushort4*)(gdst + (size_t)o * KK + cc2 * 4) = *(const ushort4*)(ot + o * 132 + cc2 * 4);
    }
  }
}

// ---- big GEMM (proven config, verbatim): out[2048][512] += Tb * WbT^T
// 128x128 tile, BK=64, split-K=16 (1024 blocks, 4/CU), single-buffer,
// 128B-pitch XOR swizzle (conflicts 0), ks in low bx bits (co-XCD A-sharing).
__global__ __launch_bounds__(256, 4) void gemm_kern(const unsigned short* __restrict__ A,
                                                    const unsigned short* __restrict__ Bt,
                                                    float* __restrict__ out) {
  __shared__ unsigned short As[128 * 64];   // 16 KB, row pitch 128 B
  __shared__ unsigned short Bs[128 * 64];   // 16 KB
  int bx = blockIdx.x;                      // 16 ks * 4 nt * 16 mt = 1024
  int ks = bx & 15, nt = (bx >> 4) & 3, mt = bx >> 6;
  int m0 = mt * 128, n0 = nt * 128, k0 = ks * 2048;
  int t = threadIdx.x;
  int wid = t >> 6, lane = t & 63, q = lane >> 4, l16 = lane & 15;
  int wm = (wid & 1) * 64, wn = (wid >> 1) * 64;
  f32x4 acc[4][4] = {};
  int srow = t >> 3;
  int cg = (t & 7) ^ (srow & 7);
  const char* gabase = (const char*)(A + (size_t)m0 * KK + k0) + (size_t)srow * 65536 + cg * 16;
  const char* gbbase = (const char*)(Bt + (size_t)n0 * KK + k0) + (size_t)srow * 65536 + cg * 16;
  int sw0 = q ^ (l16 & 7);
  int sw1 = (4 | q) ^ (l16 & 7);
#pragma unroll 1
  for (int kc = 0; kc < 2048; kc += 64) {
    const char* ga = gabase + (size_t)kc * 2;
    const char* gb = gbbase + (size_t)kc * 2;
#pragma unroll
    for (int j = 0; j < 4; j++) {
      gld16((char*)As + (j * 256 + t) * 16, ga + (size_t)j * 32 * 65536);
      gld16((char*)Bs + (j * 256 + t) * 16, gb + (size_t)j * 32 * 65536);
    }
    __syncthreads();
#pragma unroll
    for (int ks2 = 0; ks2 < 2; ks2++) {
      int slot = ks2 ? sw1 : sw0;
      bf16x8 af[4], bfr[4];
#pragma unroll
      for (int fr = 0; fr < 4; fr++)
        af[fr] = *(const bf16x8*)(As + (wm + fr * 16 + l16) * 64 + slot * 8);
#pragma unroll
      for (int fc = 0; fc < 4; fc++)
        bfr[fc] = *(const bf16x8*)(Bs + (wn + fc * 16 + l16) * 64 + slot * 8);
#pragma unroll
      for (int fr = 0; fr < 4; fr++)
#pragma unroll
        for (int fc = 0; fc < 4; fc++)
          acc[fr][fc] = __builtin_amdgcn_mfma_f32_16x16x32_bf16(af[fr], bfr[fc], acc[fr][fc], 0, 0, 0);
    }
    __syncthreads();
  }
#pragma unroll
  for (int fr = 0; fr < 4; fr++)
#pragma unroll
    for (int fc = 0; fc < 4; fc++)
#pragma unroll
      for (int r = 0; r < 4; r++)
        atomicAdd(&out[(size_t)(m0 + wm + fr * 16 + q * 4 + r) * 512 + n0 + wn + fc * 16 + l16],
                  acc[fr][fc][r]);
}

// ---- fp32 fallback (only if ws too small)
__global__ __launch_bounds__(256) void fallback_kern(const float* __restrict__ x,
                                                     const float* __restrict__ W,
                                                     const float* __restrict__ coeff,
                                                     float* __restrict__ out) {
  __shared__ float ev[64][129];
  int b = blockIdx.x >> 6, k = blockIdx.x & 63;
  int t = threadIdx.x, dl = t & 127, half = t >> 7;
  const float* xb = x + (size_t)b * 64 * 512;
  const float* Wk = W + (size_t)k * 512 * 512;
  for (int dc = 0; dc < 4; dc++) {
    int d = dc * 128 + dl;
    for (int i = half * 32; i < half * 32 + 32; i++) {
      float acc = 0.f;
      const float* xr = xb + (size_t)i * 512;
#pragma unroll 4
      for (int e = 0; e < 512; e++) acc += xr[e] * Wk[(size_t)e * 512 + d];
      ev[i][dl] = acc;
    }
    __syncthreads();
    for (int o = half * 32; o < half * 32 + 32; o++) {
      float s = 0.f;
#pragma unroll 8
      for (int i = 0; i < 64; i++) s += coeff[((size_t)o * 64 + i) * 64 + k] * ev[i][dl];
      atomicAdd(&out[((size_t)(b * 64 + o)) * 512 + d], s);
    }
    __syncthreads();
  }
}

extern "C" void kernel_launch(void* const* d_in, const int* in_sizes, int n_in,
                              void* d_out, int out_size, void* d_ws, size_t ws_size,
                              hipStream_t stream) {
  const float* x = (const float*)d_in[0];
  const float* W = (const float*)d_in[1];
  const float* coeff = (const float*)d_in[2];
  float* out = (float*)d_out;
  const size_t OFF_XT = 33554432;            // WbT: 512*32768*2
  const size_t OFF_CB = OFF_XT + 2097152;    // xT : 32*512*64*2
  const size_t OFF_TB = OFF_CB + 524288;     // cb : 64*64*64*2
  const size_t NEED = OFF_TB + 134217728;    // Tb : 2048*32768*2

  hipMemsetAsync(d_out, 0, (size_t)out_size * sizeof(float), stream);
  if (ws_size >= NEED) {
    unsigned short* WbT = (unsigned short*)d_ws;
    unsigned short* xT  = (unsigned short*)((char*)d_ws + OFF_XT);
    unsigned short* cb  = (unsigned short*)((char*)d_ws + OFF_CB);
    unsigned short* Tb  = (unsigned short*)((char*)d_ws + OFF_TB);
    convXC<<<192, 256, 0, stream>>>(x, coeff, xT, cb);
    convW<<<4096, 256, 0, stream>>>(W, WbT);
    tkern<<<2048, 256, 0, stream>>>(xT, cb, Tb);
    gemm_kern<<<1024, 256, 0, stream>>>(Tb, WbT, out);
  } else {
    fallback_kern<<<2048, 256, 0, stream>>>(x, W, coeff, out);
  }
}

// Round 8
// 228.974 us; speedup vs baseline: 1.1258x; 1.0493x over previous
//
#include <hip/hip_runtime.h>

// Problem: B=32, F_IN=64, F_OUT=64, D=512, K=64
// out[(b,o),d] = sum_{k,e} T[(b,o),(k,e)] * W[k,e,d],
// T[(b,o),(k,e)] = sum_i coeff[o,i,k] * x[b,i,e]
// R8: T fused into the GEMM (Tb intermediate eliminated).

#define KK 32768

typedef __attribute__((ext_vector_type(8))) short bf16x8;
typedef __attribute__((ext_vector_type(4))) float f32x4;

__device__ __forceinline__ unsigned short f2bf(float f) {
  unsigned int u = __float_as_uint(f);
  return (unsigned short)((u + 0x7FFFu + ((u >> 16) & 1u)) >> 16);  // RNE
}

__device__ __forceinline__ void gld16(void* lds, const void* g) {
  __builtin_amdgcn_global_load_lds((const __attribute__((address_space(1))) void*)g,
                                   (__attribute__((address_space(3))) void*)lds,
                                   16, 0, 0);
}

// ---- convert W fp32 [64][512(e)][512(d)] -> WbT bf16 [512(d)][64*512 (k,e)]
__global__ __launch_bounds__(256) void convW(const float* __restrict__ W,
                                             unsigned short* __restrict__ WbT) {
  __shared__ float tile[64][65];
  int bx = blockIdx.x;                 // 64 k * 8 et * 8 dt = 4096
  int k = bx >> 6, et = (bx >> 3) & 7, dt = bx & 7;
  int t = threadIdx.x;
  const float* src = W + ((size_t)k * 512 + (size_t)et * 64) * 512 + dt * 64;
  int rr = t >> 6, cc = t & 63;
#pragma unroll
  for (int p = 0; p < 16; p++) {
    int e = p * 4 + rr;
    tile[e][cc] = src[(size_t)e * 512 + cc];
  }
  __syncthreads();
  int dl = t >> 4, eg = t & 15;
#pragma unroll
  for (int p = 0; p < 4; p++) {
    int d = p * 16 + dl;
    ushort4 v;
    v.x = f2bf(tile[eg * 4 + 0][d]);
    v.y = f2bf(tile[eg * 4 + 1][d]);
    v.z = f2bf(tile[eg * 4 + 2][d]);
    v.w = f2bf(tile[eg * 4 + 3][d]);
    *(ushort4*)(WbT + (size_t)(dt * 64 + d) * KK + k * 512 + et * 64 + eg * 4) = v;
  }
}

// ---- fused convX + convC (one launch)
__global__ __launch_bounds__(256) void convXC(const float* __restrict__ x,
                                              const float* __restrict__ c,
                                              unsigned short* __restrict__ xT,
                                              unsigned short* __restrict__ cb) {
  __shared__ unsigned short lds[64 * 130];
  int t = threadIdx.x;
  if (blockIdx.x < 128) {
    int bx = blockIdx.x;                // 32 b * 4 ec
    int b = bx >> 2, ec = bx & 3;
    const float* src = x + (size_t)b * 32768 + ec * 128;
#pragma unroll
    for (int j = 0; j < 32; j++) {
      int idx = j * 256 + t;            // 64 i x 128 e
      int i = idx >> 7, e = idx & 127;
      lds[i * 130 + e] = f2bf(src[(size_t)i * 512 + e]);
    }
    __syncthreads();
    unsigned short* dst = xT + (size_t)b * 32768 + ec * 128 * 64;
#pragma unroll
    for (int j = 0; j < 32; j++) {
      int idx = j * 256 + t;            // 128 e x 64 i
      int e = idx >> 6, i = idx & 63;
      dst[idx] = lds[i * 130 + e];
    }
  } else {
    int rb = blockIdx.x - 128;          // 64 blocks over r = o*64+i
    const float* src = c + (size_t)rb * 4096;
#pragma unroll
    for (int j = 0; j < 16; j++) {
      int idx = j * 256 + t;
      int r = idx >> 6, k = idx & 63;
      lds[r * 66 + k] = f2bf(src[idx]);
    }
    __syncthreads();
#pragma unroll
    for (int j = 0; j < 16; j++) {
      int idx = j * 256 + t;
      int k = idx >> 6, r = idx & 63;
      cb[(size_t)k * 4096 + rb * 64 + r] = lds[r * 66 + k];
    }
  }
}

// ---- fused T+GEMM: out[2048][512] += (coeff x)[m][kk] * WbT[n][kk]^T
// Block (mt 16, nt 4, ks 16) = 1024 blocks. m-tile 128 = 2 b x 64 o; kk range
// 2048 = 4 k-words x 512 e (8 e-chunks of 64). Per (ec,k): T-MFMA computes the
// A-tile in-block (operand-swapped: D rows = e -> ds_write_b64 into swizzled As),
// then the standard 128-MFMA main step. As aliases xe (ax frags live in regs).
// LDS 48 KB -> 3 blocks/CU. ck ping-pong prefetched across the mid barrier.
__global__ __launch_bounds__(256, 3) void fused_kern(const unsigned short* __restrict__ xT,
                                                     const unsigned short* __restrict__ cb,
                                                     const unsigned short* __restrict__ Bt,
                                                     float* __restrict__ out) {
  __shared__ unsigned short u[128 * 64];     // xe (per-ec preamble) / As (k-loop), 16 KB
  __shared__ unsigned short Bs[128 * 64];    // 16 KB
  __shared__ unsigned short ck[2][64 * 64];  // 8 KB x2
  int bx = blockIdx.x;                       // ks + nt*16 + mt*64 (ks low: co-XCD B-sharing)
  int ks = bx & 15, nt = (bx >> 4) & 3, mt = bx >> 6;
  int m0 = mt * 128, n0 = nt * 128, kw0 = ks * 4, b0 = mt * 2;
  int t = threadIdx.x;
  int wid = t >> 6, lane = t & 63, q = lane >> 4, l16 = lane & 15;
  int wmb = wid & 1;                         // b_l for T-phase; main wm = wmb*64
  int weh = wid >> 1;                        // e-half for T-phase; main wn = weh*64
  int srow = t >> 3;                         // 0..31 staging row
  int cg = (t & 7) ^ (srow & 7);             // row&7 == srow&7 (rows step by 32)
  // block preamble: ck[0] for word kw0
  {
    const unsigned short* gc = cb + (size_t)kw0 * 4096;
#pragma unroll
    for (int j = 0; j < 2; j++)
      gld16((char*)ck[0] + (j * 256 + t) * 16, gc + (j * 32 + srow) * 64 + cg * 8);
  }
  f32x4 acc[4][4] = {};
#pragma unroll 1
  for (int ec = 0; ec < 8; ec++) {
    // stage xe into u: row = b_l*64 + e_l, src xT[b0+b_l][ec*64+e_l][.]
#pragma unroll
    for (int j = 0; j < 4; j++) {
      int row = j * 32 + srow;
      int bl = row >> 6, el = row & 63;
      gld16((char*)u + (j * 256 + t) * 16,
            xT + (size_t)(b0 + bl) * 32768 + (size_t)(ec * 64 + el) * 64 + cg * 8);
    }
    __syncthreads();                         // xe (+ck if pending) ready
    // ax frags: A[m=e][k=i], rows wmb*64 + weh*32 + ef*16 + l16
    bf16x8 ax[2][2];
#pragma unroll
    for (int ef = 0; ef < 2; ef++)
#pragma unroll
      for (int ks2 = 0; ks2 < 2; ks2++) {
        int row = wmb * 64 + weh * 32 + ef * 16 + l16;
        int s2 = (ks2 * 4 + q) ^ (row & 7);
        ax[ef][ks2] = *(const bf16x8*)(u + row * 64 + s2 * 8);
      }
    __syncthreads();                         // ax-read guard (As aliases u)
#pragma unroll 1
    for (int k = 0; k < 4; k++) {
      int seq = ec * 4 + k, cur = seq & 1;
      // stage Bs: rows n0+row, cols (kw0+k)*512 + ec*64
      const unsigned short* gb = Bt + (size_t)n0 * KK + (size_t)(kw0 + k) * 512 + ec * 64;
#pragma unroll
      for (int j = 0; j < 4; j++) {
        int row = j * 32 + srow;
        gld16((char*)Bs + (j * 256 + t) * 16, gb + (size_t)row * KK + cg * 8);
      }
      if (seq < 31) {                        // prefetch next ck across the mid barrier
        int nk = (k < 3) ? k + 1 : 0;
        const unsigned short* gc = cb + (size_t)(kw0 + nk) * 4096;
#pragma unroll
        for (int j = 0; j < 2; j++)
          gld16((char*)ck[cur ^ 1] + (j * 256 + t) * 16, gc + (j * 32 + srow) * 64 + cg * 8);
      }
      // T-phase: D[e][o] = sum_i xe[e][i] * ck[o][i]
      const unsigned short* ckk = ck[cur];
      bf16x8 bc[4][2];
#pragma unroll
      for (int of = 0; of < 4; of++)
#pragma unroll
        for (int ks2 = 0; ks2 < 2; ks2++) {
          int o = of * 16 + l16;
          int s2 = (ks2 * 4 + q) ^ (o & 7);
          bc[of][ks2] = *(const bf16x8*)(ckk + o * 64 + s2 * 8);
        }
      f32x4 td[2][4] = {};
#pragma unroll
      for (int ef = 0; ef < 2; ef++)
#pragma unroll
        for (int of = 0; of < 4; of++)
#pragma unroll
          for (int ks2 = 0; ks2 < 2; ks2++)
            td[ef][of] = __builtin_amdgcn_mfma_f32_16x16x32_bf16(ax[ef][ks2], bc[of][ks2],
                                                                 td[ef][of], 0, 0, 0);
      // write As (alias u), swizzled: row = wmb*64+of*16+l16, col c0 = weh*32+ef*16+q*4
#pragma unroll
      for (int ef = 0; ef < 2; ef++)
#pragma unroll
        for (int of = 0; of < 4; of++) {
          int row = wmb * 64 + of * 16 + l16;
          int c0 = weh * 32 + ef * 16 + q * 4;
          int phys = ((c0 >> 3) ^ (row & 7)) * 8 + (c0 & 7);
          ushort4 v;
          v.x = f2bf(td[ef][of][0]);
          v.y = f2bf(td[ef][of][1]);
          v.z = f2bf(td[ef][of][2]);
          v.w = f2bf(td[ef][of][3]);
          *(ushort4*)(u + row * 64 + phys) = v;
        }
      __syncthreads();                       // mid: drains Bs/ck gld16 + As ds_writes
      // main: acc += As[wm..][.] * Bs[wn..][.]
#pragma unroll
      for (int ks2 = 0; ks2 < 2; ks2++) {
        int slot = ks2 * 4 + q;
        bf16x8 af[4], bfr[4];
#pragma unroll
        for (int fr = 0; fr < 4; fr++) {
          int row = wmb * 64 + fr * 16 + l16;
          af[fr] = *(const bf16x8*)(u + row * 64 + (slot ^ (row & 7)) * 8);
        }
#pragma unroll
        for (int fc = 0; fc < 4; fc++) {
          int row = weh * 64 + fc * 16 + l16;
          bfr[fc] = *(const bf16x8*)(Bs + row * 64 + (slot ^ (row & 7)) * 8);
        }
#pragma unroll
        for (int fr = 0; fr < 4; fr++)
#pragma unroll
          for (int fc = 0; fc < 4; fc++)
            acc[fr][fc] = __builtin_amdgcn_mfma_f32_16x16x32_bf16(af[fr], bfr[fc],
                                                                  acc[fr][fc], 0, 0, 0);
      }
      __syncthreads();                       // trailing: guard As/Bs/ck rewrites
    }
  }
#pragma unroll
  for (int fr = 0; fr < 4; fr++)
#pragma unroll
    for (int fc = 0; fc < 4; fc++)
#pragma unroll
      for (int r = 0; r < 4; r++)
        atomicAdd(&out[(size_t)(m0 + wmb * 64 + fr * 16 + q * 4 + r) * 512
                       + n0 + weh * 64 + fc * 16 + l16],
                  acc[fr][fc][r]);
}

// ---- fp32 fallback (only if ws too small)
__global__ __launch_bounds__(256) void fallback_kern(const float* __restrict__ x,
                                                     const float* __restrict__ W,
                                                     const float* __restrict__ coeff,
                                                     float* __restrict__ out) {
  __shared__ float ev[64][129];
  int b = blockIdx.x >> 6, k = blockIdx.x & 63;
  int t = threadIdx.x, dl = t & 127, half = t >> 7;
  const float* xb = x + (size_t)b * 64 * 512;
  const float* Wk = W + (size_t)k * 512 * 512;
  for (int dc = 0; dc < 4; dc++) {
    int d = dc * 128 + dl;
    for (int i = half * 32; i < half * 32 + 32; i++) {
      float acc = 0.f;
      const float* xr = xb + (size_t)i * 512;
#pragma unroll 4
      for (int e = 0; e < 512; e++) acc += xr[e] * Wk[(size_t)e * 512 + d];
      ev[i][dl] = acc;
    }
    __syncthreads();
    for (int o = half * 32; o < half * 32 + 32; o++) {
      float s = 0.f;
#pragma unroll 8
      for (int i = 0; i < 64; i++) s += coeff[((size_t)o * 64 + i) * 64 + k] * ev[i][dl];
      atomicAdd(&out[((size_t)(b * 64 + o)) * 512 + d], s);
    }
    __syncthreads();
  }
}

extern "C" void kernel_launch(void* const* d_in, const int* in_sizes, int n_in,
                              void* d_out, int out_size, void* d_ws, size_t ws_size,
                              hipStream_t stream) {
  const float* x = (const float*)d_in[0];
  const float* W = (const float*)d_in[1];
  const float* coeff = (const float*)d_in[2];
  float* out = (float*)d_out;
  const size_t OFF_XT = 33554432;            // WbT: 512*32768*2
  const size_t OFF_CB = OFF_XT + 2097152;    // xT : 32*512*64*2
  const size_t NEED = OFF_CB + 524288;       // cb : 64*64*64*2  (no Tb anymore)

  hipMemsetAsync(d_out, 0, (size_t)out_size * sizeof(float), stream);
  if (ws_size >= NEED) {
    unsigned short* WbT = (unsigned short*)d_ws;
    unsigned short* xT  = (unsigned short*)((char*)d_ws + OFF_XT);
    unsigned short* cb  = (unsigned short*)((char*)d_ws + OFF_CB);
    convXC<<<192, 256, 0, stream>>>(x, coeff, xT, cb);
    convW<<<4096, 256, 0, stream>>>(W, WbT);
    fused_kern<<<1024, 256, 0, stream>>>(xT, cb, WbT, out);
  } else {
    fallback_kern<<<2048, 256, 0, stream>>>(x, W, coeff, out);
  }
}

// Round 9
// 221.862 us; speedup vs baseline: 1.1619x; 1.0321x over previous
//
#include <hip/hip_runtime.h>
#include <hip/hip_bf16.h>

// Problem: B=32, F_IN=64, F_OUT=64, D=512, K=64
// out[(b,o),d] = sum_{k,e} T[(b,o),(k,e)] * W[k,e,d],
// T[(b,o),(k,e)] = sum_i coeff[o,i,k] * x[b,i,e]
// R9: fused T+GEMM, 128x256 block, 64x128 wave tiles, np=2 ks=16.

#define KK 32768

typedef __attribute__((ext_vector_type(8))) short bf16x8;
typedef __attribute__((ext_vector_type(4))) float f32x4;

__device__ __forceinline__ unsigned short f2bf(float f) {
  unsigned int u = __float_as_uint(f);
  return (unsigned short)((u + 0x7FFFu + ((u >> 16) & 1u)) >> 16);  // RNE
}

__device__ __forceinline__ unsigned int pkbf2(float a, float b) {
  __hip_bfloat162 h = __float22bfloat162_rn(make_float2(a, b));  // v_cvt_pk_bf16_f32
  return *(unsigned int*)&h;
}

__device__ __forceinline__ void gld16(void* lds, const void* g) {
  __builtin_amdgcn_global_load_lds((const __attribute__((address_space(1))) void*)g,
                                   (__attribute__((address_space(3))) void*)lds,
                                   16, 0, 0);
}

// ---- convert W fp32 [64][512(e)][512(d)] -> WbT bf16 [512(d)][64*512 (k,e)]
__global__ __launch_bounds__(256) void convW(const float* __restrict__ W,
                                             unsigned short* __restrict__ WbT) {
  __shared__ float tile[64][65];
  int bx = blockIdx.x;                 // 64 k * 8 et * 8 dt = 4096
  int k = bx >> 6, et = (bx >> 3) & 7, dt = bx & 7;
  int t = threadIdx.x;
  const float* src = W + ((size_t)k * 512 + (size_t)et * 64) * 512 + dt * 64;
  int rr = t >> 6, cc = t & 63;
#pragma unroll
  for (int p = 0; p < 16; p++) {
    int e = p * 4 + rr;
    tile[e][cc] = src[(size_t)e * 512 + cc];
  }
  __syncthreads();
  int dl = t >> 4, eg = t & 15;
#pragma unroll
  for (int p = 0; p < 4; p++) {
    int d = p * 16 + dl;
    ushort4 v;
    v.x = f2bf(tile[eg * 4 + 0][d]);
    v.y = f2bf(tile[eg * 4 + 1][d]);
    v.z = f2bf(tile[eg * 4 + 2][d]);
    v.w = f2bf(tile[eg * 4 + 3][d]);
    *(ushort4*)(WbT + (size_t)(dt * 64 + d) * KK + k * 512 + et * 64 + eg * 4) = v;
  }
}

// ---- fused convX + convC (one launch)
__global__ __launch_bounds__(256) void convXC(const float* __restrict__ x,
                                              const float* __restrict__ c,
                                              unsigned short* __restrict__ xT,
                                              unsigned short* __restrict__ cb) {
  __shared__ unsigned short lds[64 * 130];
  int t = threadIdx.x;
  if (blockIdx.x < 128) {
    int bx = blockIdx.x;                // 32 b * 4 ec
    int b = bx >> 2, ec = bx & 3;
    const float* src = x + (size_t)b * 32768 + ec * 128;
#pragma unroll
    for (int j = 0; j < 32; j++) {
      int idx = j * 256 + t;            // 64 i x 128 e
      int i = idx >> 7, e = idx & 127;
      lds[i * 130 + e] = f2bf(src[(size_t)i * 512 + e]);
    }
    __syncthreads();
    unsigned short* dst = xT + (size_t)b * 32768 + ec * 128 * 64;
#pragma unroll
    for (int j = 0; j < 32; j++) {
      int idx = j * 256 + t;            // 128 e x 64 i
      int e = idx >> 6, i = idx & 63;
      dst[idx] = lds[i * 130 + e];
    }
  } else {
    int rb = blockIdx.x - 128;          // 64 blocks over r = o*64+i
    const float* src = c + (size_t)rb * 4096;
#pragma unroll
    for (int j = 0; j < 16; j++) {
      int idx = j * 256 + t;
      int r = idx >> 6, k = idx & 63;
      lds[r * 66 + k] = f2bf(src[idx]);
    }
    __syncthreads();
#pragma unroll
    for (int j = 0; j < 16; j++) {
      int idx = j * 256 + t;
      int k = idx >> 6, r = idx & 63;
      cb[(size_t)k * 4096 + rb * 64 + r] = lds[r * 66 + k];
    }
  }
}

// ---- fused T+GEMM v2: out[2048][512] += (coeff x)[m][kk] * WbT[n][kk]^T
// Grid 512 = mt(16) x np(2) x ks(16); block-tile 128m x 256n, kk-slice 2048
// (4 k-words x 8 e-chunks of 64). 4 waves of 64m x 128n (+33% FLOP/LDS-byte
// vs 64x64). ck: all 4 k-words staged once per block. xe staged per ec,
// reused over 4 k-words; As aliases xe after ax extraction. LDS 80 KB ->
// 2 blocks/CU. T recompute x2 (np) -> 86 GF total MFMA.
__global__ __launch_bounds__(256, 2) void fused_kern(const unsigned short* __restrict__ xT,
                                                     const unsigned short* __restrict__ cb,
                                                     const unsigned short* __restrict__ Bt,
                                                     float* __restrict__ out) {
  __shared__ unsigned short u[128 * 64];     // xe (per-ec) / As (k-loop), 16 KB
  __shared__ unsigned short Bs[256 * 64];    // 32 KB
  __shared__ unsigned short ck[4 * 64 * 64]; // 32 KB (4 k-words, whole block)
  int bx = blockIdx.x;                       // [mt:4][np:1][ks:4]; mt-siblings co-XCD
  int ks = bx & 15, np = (bx >> 4) & 1, mt = bx >> 5;
  int m0 = mt * 128, n0 = np * 256, kw0 = ks * 4, b0 = mt * 2;
  int t = threadIdx.x;
  int wid = t >> 6, lane = t & 63, q = lane >> 4, l16 = lane & 15;
  int wmb = wid & 1;                         // m-half (also b index in T-phase)
  int wnh = wid >> 1;                        // n-half (also o-tile-pair in T-phase)
  int srow = t >> 3;                         // 0..31 staging row
  int cg = (t & 7) ^ (srow & 7);
  // block preamble: all 4 ck words (32 KB, 8 gld16 rounds)
  {
    const unsigned short* gc = cb + (size_t)kw0 * 4096;
#pragma unroll
    for (int j = 0; j < 8; j++) {
      int row = j * 32 + srow;               // row = kj*64 + o; row&7 == o&7
      gld16((char*)ck + (j * 256 + t) * 16, gc + (size_t)row * 64 + cg * 8);
    }
  }
  f32x4 acc[4][8] = {};                      // wave 64m x 128n
#pragma unroll 1
  for (int ec = 0; ec < 8; ec++) {
    // stage xe into u: row = b_l*64 + e_l
#pragma unroll
    for (int j = 0; j < 4; j++) {
      int row = j * 32 + srow;
      int bl = row >> 6, el = row & 63;
      gld16((char*)u + (j * 256 + t) * 16,
            xT + (size_t)(b0 + bl) * 32768 + (size_t)(ec * 64 + el) * 64 + cg * 8);
    }
    __syncthreads();                         // xe (+ck on ec=0) ready
    // ax frags: A[m=e][k=i] for this wave's b = wmb, all 4 e-tiles
    bf16x8 ax[4][2];
#pragma unroll
    for (int et = 0; et < 4; et++)
#pragma unroll
      for (int ks2 = 0; ks2 < 2; ks2++) {
        int row = wmb * 64 + et * 16 + l16;
        int s2 = (ks2 * 4 + q) ^ (row & 7);
        ax[et][ks2] = *(const bf16x8*)(u + row * 64 + s2 * 8);
      }
    __syncthreads();                         // ax reads done; u free for As
#pragma unroll 1
    for (int k = 0; k < 4; k++) {
      // stage Bs: 256 d-rows x 64 kk (32 KB, 8 rounds)
      const unsigned short* gb = Bt + (size_t)n0 * KK + (size_t)(kw0 + k) * 512 + ec * 64;
#pragma unroll
      for (int j = 0; j < 8; j++) {
        int row = j * 32 + srow;
        gld16((char*)Bs + (j * 256 + t) * 16, gb + (size_t)row * KK + cg * 8);
      }
      // T-phase: this wave covers b = wmb, o-tiles {wnh*2, wnh*2+1}
      const unsigned short* ckk = ck + k * 4096;
      bf16x8 bc[2][2];
#pragma unroll
      for (int otl = 0; otl < 2; otl++)
#pragma unroll
        for (int ks2 = 0; ks2 < 2; ks2++) {
          int o = (wnh * 2 + otl) * 16 + l16;
          int s2 = (ks2 * 4 + q) ^ (o & 7);
          bc[otl][ks2] = *(const bf16x8*)(ckk + o * 64 + s2 * 8);
        }
      f32x4 td[4][2] = {};                   // [et][otl], D[m=e][n=o]
#pragma unroll
      for (int et = 0; et < 4; et++)
#pragma unroll
        for (int otl = 0; otl < 2; otl++)
#pragma unroll
          for (int ks2 = 0; ks2 < 2; ks2++)
            td[et][otl] = __builtin_amdgcn_mfma_f32_16x16x32_bf16(ax[et][ks2], bc[otl][ks2],
                                                                  td[et][otl], 0, 0, 0);
      // write As (alias u): row = wmb*64 + ot*16 + l16 (o), col c0 = et*16 + q*4 (e)
#pragma unroll
      for (int et = 0; et < 4; et++)
#pragma unroll
        for (int otl = 0; otl < 2; otl++) {
          int row = wmb * 64 + (wnh * 2 + otl) * 16 + l16;
          int c0 = et * 16 + q * 4;
          int phys = ((c0 >> 3) ^ (row & 7)) * 8 + (c0 & 7);
          uint2 v;
          v.x = pkbf2(td[et][otl][0], td[et][otl][1]);
          v.y = pkbf2(td[et][otl][2], td[et][otl][3]);
          *(uint2*)(u + row * 64 + phys) = v;
        }
      __syncthreads();                       // mid: drains Bs gld16 + As ds_writes
      // main: acc += As[wm..][kk] * Bs[wn..][kk], wave 64m x 128n
#pragma unroll
      for (int ks2 = 0; ks2 < 2; ks2++) {
        bf16x8 af[4], bfr[8];
#pragma unroll
        for (int mf = 0; mf < 4; mf++) {
          int row = wmb * 64 + mf * 16 + l16;
          af[mf] = *(const bf16x8*)(u + row * 64 + (((ks2 * 4 + q) ^ (row & 7))) * 8);
        }
#pragma unroll
        for (int nf = 0; nf < 8; nf++) {
          int row = wnh * 128 + nf * 16 + l16;
          bfr[nf] = *(const bf16x8*)(Bs + row * 64 + (((ks2 * 4 + q) ^ (row & 7))) * 8);
        }
#pragma unroll
        for (int mf = 0; mf < 4; mf++)
#pragma unroll
          for (int nf = 0; nf < 8; nf++)
            acc[mf][nf] = __builtin_amdgcn_mfma_f32_16x16x32_bf16(af[mf], bfr[nf],
                                                                  acc[mf][nf], 0, 0, 0);
      }
      __syncthreads();                       // trailing: As/Bs free for rewrite
    }
  }
#pragma unroll
  for (int mf = 0; mf < 4; mf++)
#pragma unroll
    for (int nf = 0; nf < 8; nf++)
#pragma unroll
      for (int r = 0; r < 4; r++)
        atomicAdd(&out[(size_t)(m0 + wmb * 64 + mf * 16 + q * 4 + r) * 512
                       + n0 + wnh * 128 + nf * 16 + l16],
                  acc[mf][nf][r]);
}

// ---- fp32 fallback (only if ws too small)
__global__ __launch_bounds__(256) void fallback_kern(const float* __restrict__ x,
                                                     const float* __restrict__ W,
                                                     const float* __restrict__ coeff,
                                                     float* __restrict__ out) {
  __shared__ float ev[64][129];
  int b = blockIdx.x >> 6, k = blockIdx.x & 63;
  int t = threadIdx.x, dl = t & 127, half = t >> 7;
  const float* xb = x + (size_t)b * 64 * 512;
  const float* Wk = W + (size_t)k * 512 * 512;
  for (int dc = 0; dc < 4; dc++) {
    int d = dc * 128 + dl;
    for (int i = half * 32; i < half * 32 + 32; i++) {
      float acc = 0.f;
      const float* xr = xb + (size_t)i * 512;
#pragma unroll 4
      for (int e = 0; e < 512; e++) acc += xr[e] * Wk[(size_t)e * 512 + d];
      ev[i][dl] = acc;
    }
    __syncthreads();
    for (int o = half * 32; o < half * 32 + 32; o++) {
      float s = 0.f;
#pragma unroll 8
      for (int i = 0; i < 64; i++) s += coeff[((size_t)o * 64 + i) * 64 + k] * ev[i][dl];
      atomicAdd(&out[((size_t)(b * 64 + o)) * 512 + d], s);
    }
    __syncthreads();
  }
}

extern "C" void kernel_launch(void* const* d_in, const int* in_sizes, int n_in,
                              void* d_out, int out_size, void* d_ws, size_t ws_size,
                              hipStream_t stream) {
  const float* x = (const float*)d_in[0];
  const float* W = (const float*)d_in[1];
  const float* coeff = (const float*)d_in[2];
  float* out = (float*)d_out;
  const size_t OFF_XT = 33554432;            // WbT: 512*32768*2
  const size_t OFF_CB = OFF_XT + 2097152;    // xT : 32*512*64*2
  const size_t NEED = OFF_CB + 524288;       // cb : 64*64*64*2

  hipMemsetAsync(d_out, 0, (size_t)out_size * sizeof(float), stream);
  if (ws_size >= NEED) {
    unsigned short* WbT = (unsigned short*)d_ws;
    unsigned short* xT  = (unsigned short*)((char*)d_ws + OFF_XT);
    unsigned short* cb  = (unsigned short*)((char*)d_ws + OFF_CB);
    convXC<<<192, 256, 0, stream>>>(x, coeff, xT, cb);
    convW<<<4096, 256, 0, stream>>>(W, WbT);
    fused_kern<<<512, 256, 0, stream>>>(xT, cb, WbT, out);
  } else {
    fallback_kern<<<2048, 256, 0, stream>>>(x, W, coeff, out);
  }
}